// Round 16
// baseline (239.687 us; speedup 1.0000x reference)
//
#include <hip/hip_runtime.h>
#include <math.h>

#define N_NODES 50000
#define N_EDGES 800000
#define NEG_SLOPE 0.2f

typedef __attribute__((ext_vector_type(8))) short bf16x8;
typedef __attribute__((ext_vector_type(4))) float f32x4;
typedef __attribute__((ext_vector_type(4))) _Float16 half4;

__device__ inline unsigned short f32_to_bf16_rn(float x) {
    unsigned u = __builtin_bit_cast(unsigned, x);
    unsigned r = u + 0x7fffu + ((u >> 16) & 1u);
    return (unsigned short)(r >> 16);
}
__device__ inline float bf16_bits_to_f32(unsigned short h) {
    unsigned u = ((unsigned)h) << 16;
    return __builtin_bit_cast(float, u);
}
__device__ inline void load_lds16(const void* g, void* l) {
    __builtin_amdgcn_global_load_lds(
        (const __attribute__((address_space(1))) void*)g,
        (__attribute__((address_space(3))) void*)l, 16, 0, 0);
}

// ---------------- bodies ----------------

__device__ __forceinline__ void count_body(int bb, const int* __restrict__ dst,
                                           int* __restrict__ deg) {
    int i = bb * 256 + threadIdx.x;
    if (i < N_EDGES) atomicAdd(&deg[dst[i]], 1);
}

__device__ __forceinline__ void convert_body(int n, const float* __restrict__ W,
                                             unsigned short* __restrict__ Th,
                                             unsigned short* __restrict__ Tl) {
    int k = threadIdx.x;
    float x = W[k * 256 + n];
    unsigned short h = f32_to_bf16_rn(x);
    float lo = x - bf16_bits_to_f32(h);
    size_t idx = ((size_t)(k >> 3) * 256 + n) * 8 + (k & 7);
    Th[idx] = h;
    Tl[idx] = f32_to_bf16_rn(lo);
}

// per-block scan + one global atomic: arbitrary-order disjoint segments
__device__ __forceinline__ void assign_body(int bb, const int* __restrict__ deg,
                                            int* __restrict__ offs,
                                            int* __restrict__ cursor,
                                            int* __restrict__ gcounter) {
    __shared__ int buf[256];
    __shared__ int base;
    int tid = threadIdx.x;
    int v = bb * 256 + tid;
    int d = (v < N_NODES) ? deg[v] : 0;
    buf[tid] = d;
    __syncthreads();
    for (int off = 1; off < 256; off <<= 1) {
        int x = (tid >= off) ? buf[tid - off] : 0;
        __syncthreads();
        buf[tid] += x;
        __syncthreads();
    }
    if (tid == 255) base = atomicAdd(gcounter, buf[255]);
    __syncthreads();
    if (v < N_NODES) {
        int start = base + buf[tid] - d;
        offs[v] = start;
        cursor[v] = start;
    }
}

__global__ void scatter_edges(const int* __restrict__ src, const int* __restrict__ dst,
                              int* __restrict__ cursor, int* __restrict__ src_csr) {
    int i = blockIdx.x * 256 + threadIdx.x;
    if (i < N_EDGES) {
        int p = atomicAdd(&cursor[dst[i]], 1);
        src_csr[p] = src[i];
    }
}

// ---------------- GEMM1 body: split-bf16 MFMA, BM=64 BN=256, fused el/er ----------------

__device__ __forceinline__ void gemm1_body(int bb, const float* __restrict__ A,
                                           const unsigned short* __restrict__ BTh,
                                           const unsigned short* __restrict__ BTl,
                                           const float* __restrict__ al,
                                           const float* __restrict__ ar,
                                           _Float16* __restrict__ C,
                                           float* __restrict__ el,
                                           float* __restrict__ er, int M) {
    __shared__ unsigned short Ah[4][64][8], Al[4][64][8];
    __shared__ unsigned short Bh[4][256][8], Bl[4][256][8];
    int tid = threadIdx.x;
    int lane = tid & 63, wave = tid >> 6;
    int kgl = lane >> 4, rl = lane & 15;
    int row0 = bb * 64;

    f32x4 acc[4][4];
#pragma unroll
    for (int i = 0; i < 4; i++)
#pragma unroll
        for (int j = 0; j < 4; j++) acc[i][j] = (f32x4){0.f, 0.f, 0.f, 0.f};

    int rowA = tid >> 2, kgA = tid & 3;
    int grA = row0 + rowA;
    const float* pA = &A[(size_t)grA * 256 + kgA * 8];
    float4 x0 = make_float4(0.f, 0.f, 0.f, 0.f);
    float4 x1 = make_float4(0.f, 0.f, 0.f, 0.f);
    if (grA < M) {
        x0 = *reinterpret_cast<const float4*>(pA);
        x1 = *reinterpret_cast<const float4*>(pA + 4);
    }

    for (int step = 0; step < 8; step++) {
        int k0 = step * 32;
        {
            float xs[8] = {x0.x, x0.y, x0.z, x0.w, x1.x, x1.y, x1.z, x1.w};
            unsigned short hs[8], ls[8];
#pragma unroll
            for (int j = 0; j < 8; j++) {
                hs[j] = f32_to_bf16_rn(xs[j]);
                ls[j] = f32_to_bf16_rn(xs[j] - bf16_bits_to_f32(hs[j]));
            }
            *reinterpret_cast<bf16x8*>(&Ah[kgA][rowA][0]) = *reinterpret_cast<bf16x8*>(hs);
            *reinterpret_cast<bf16x8*>(&Al[kgA][rowA][0]) = *reinterpret_cast<bf16x8*>(ls);
        }
        int s0 = k0 >> 3;
#pragma unroll
        for (int i = 0; i < 4; i++) {
            load_lds16(&BTh[((size_t)(s0 + i) * 256 + tid) * 8], &Bh[i][wave << 6][0]);
            load_lds16(&BTl[((size_t)(s0 + i) * 256 + tid) * 8], &Bl[i][wave << 6][0]);
        }
        __syncthreads();
        if (step < 7 && grA < M) {
            x0 = *reinterpret_cast<const float4*>(pA + (step + 1) * 32);
            x1 = *reinterpret_cast<const float4*>(pA + (step + 1) * 32 + 4);
        }
        bf16x8 a_h[4], a_l[4];
#pragma unroll
        for (int mf = 0; mf < 4; mf++) {
            int row = mf * 16 + rl;
            a_h[mf] = *reinterpret_cast<bf16x8*>(&Ah[kgl][row][0]);
            a_l[mf] = *reinterpret_cast<bf16x8*>(&Al[kgl][row][0]);
        }
#pragma unroll
        for (int nf = 0; nf < 4; nf++) {
            int col = wave * 64 + nf * 16 + rl;
            bf16x8 bh = *reinterpret_cast<bf16x8*>(&Bh[kgl][col][0]);
            bf16x8 bl = *reinterpret_cast<bf16x8*>(&Bl[kgl][col][0]);
#pragma unroll
            for (int mf = 0; mf < 4; mf++) {
                acc[mf][nf] = __builtin_amdgcn_mfma_f32_16x16x32_bf16(a_h[mf], bh, acc[mf][nf], 0, 0, 0);
                acc[mf][nf] = __builtin_amdgcn_mfma_f32_16x16x32_bf16(a_h[mf], bl, acc[mf][nf], 0, 0, 0);
                acc[mf][nf] = __builtin_amdgcn_mfma_f32_16x16x32_bf16(a_l[mf], bh, acc[mf][nf], 0, 0, 0);
            }
        }
        __syncthreads();
    }
    float alv[4], arv[4];
#pragma unroll
    for (int nf = 0; nf < 4; nf++) {
        int c = wave * 64 + nf * 16 + rl;
        alv[nf] = al[c];
        arv[nf] = ar[c];
    }
#pragma unroll
    for (int mf = 0; mf < 4; mf++) {
#pragma unroll
        for (int rr = 0; rr < 4; rr++) {
            int grow = row0 + mf * 16 + (lane >> 4) * 4 + rr;
            bool ok = grow < M;
            if (ok) {
#pragma unroll
                for (int nf = 0; nf < 4; nf++) {
                    int gcol = wave * 64 + nf * 16 + rl;
                    C[(size_t)grow * 256 + gcol] = (_Float16)acc[mf][nf][rr];
                }
            }
            float e0 = acc[mf][0][rr] * alv[0] + acc[mf][1][rr] * alv[1];
            float e1 = acc[mf][2][rr] * alv[2] + acc[mf][3][rr] * alv[3];
            float f0 = acc[mf][0][rr] * arv[0] + acc[mf][1][rr] * arv[1];
            float f1 = acc[mf][2][rr] * arv[2] + acc[mf][3][rr] * arv[3];
#pragma unroll
            for (int off = 8; off >= 1; off >>= 1) {
                e0 += __shfl_down(e0, off, 16);
                e1 += __shfl_down(e1, off, 16);
                f0 += __shfl_down(f0, off, 16);
                f1 += __shfl_down(f1, off, 16);
            }
            if (rl == 0 && ok) {
                int h0 = wave * 2;
                el[grow * 8 + h0] = e0;
                el[grow * 8 + h0 + 1] = e1;
                er[grow * 8 + h0] = f0;
                er[grow * 8 + h0 + 1] = f1;
            }
        }
    }
}

// ---------------- fused launch kernels ----------------

__global__ __launch_bounds__(256) void k_count_convert(const int* __restrict__ dst,
                                                       int* __restrict__ deg,
                                                       const float* __restrict__ W1,
                                                       unsigned short* __restrict__ Th,
                                                       unsigned short* __restrict__ Tl) {
    int b = blockIdx.x;
    if (b < 3125) count_body(b, dst, deg);
    else convert_body(b - 3125, W1, Th, Tl);
}

// full gemm1 grid (782) + assign riders (196)
__global__ __launch_bounds__(256) void k_gemm1_assign(const float* __restrict__ A,
                                                      const unsigned short* __restrict__ BTh,
                                                      const unsigned short* __restrict__ BTl,
                                                      const float* __restrict__ al,
                                                      const float* __restrict__ ar,
                                                      _Float16* __restrict__ C,
                                                      float* __restrict__ el,
                                                      float* __restrict__ er, int M,
                                                      const int* __restrict__ deg,
                                                      int* __restrict__ offs,
                                                      int* __restrict__ cursor,
                                                      int* __restrict__ gcounter) {
    int b = blockIdx.x;
    if (b < 782) gemm1_body(b, A, BTh, BTl, al, ar, C, el, er, M);
    else assign_body(b - 782, deg, offs, cursor, gcounter);
}

// ---------------- layer-1 fused softmax + weighted gather (1 wave/node) ----------------

__global__ __launch_bounds__(64) void agg1_fused(const int* __restrict__ offs,
                                                 const int* __restrict__ deg_arr,
                                                 const int* __restrict__ src_csr,
                                                 const float* __restrict__ el,
                                                 const float* __restrict__ er,
                                                 const _Float16* __restrict__ h1h,
                                                 const float* __restrict__ bias1,
                                                 _Float16* __restrict__ x2) {
    __shared__ float sc[64][8];
    int v = blockIdx.x;
    int t = threadIdx.x;
    int head = t >> 3, slot = t & 7;
    int start = offs[v];
    int deg = deg_arr[v];
    int end = start + deg;
    int ncache = (deg < 64) ? deg : 64;
    float erv = er[v * 8 + head];
    float s = 0.f;
    for (int base = 0; base < ncache; base += 8) {
        int e = base + slot;
        if (e < ncache) {
            int u = src_csr[start + e];
            float x = el[u * 8 + head] + erv;
            x = (x >= 0.f) ? x : NEG_SLOPE * x;
            float ex = expf(x);
            sc[e][head] = ex;
            s += ex;
        }
    }
    for (int base = 64; base < deg; base += 8) {
        int e = base + slot;
        if (e < deg) {
            int u = src_csr[start + e];
            float x = el[u * 8 + head] + erv;
            x = (x >= 0.f) ? x : NEG_SLOPE * x;
            s += expf(x);
        }
    }
    s += __shfl_xor(s, 1);
    s += __shfl_xor(s, 2);
    s += __shfl_xor(s, 4);
    float invs = (s > 0.f) ? 1.f / s : 0.f;
    __syncthreads();
    float4 acc = make_float4(0.f, 0.f, 0.f, 0.f);
    int i = start;
    for (; i + 3 < end && (i - start) + 3 < 64; i += 4) {
        int e = i - start;
        int u0 = src_csr[i];
        int u1 = src_csr[i + 1];
        int u2 = src_csr[i + 2];
        int u3 = src_csr[i + 3];
        float a0 = sc[e][head] * invs;
        float a1 = sc[e + 1][head] * invs;
        float a2 = sc[e + 2][head] * invs;
        float a3 = sc[e + 3][head] * invs;
        half4 p0 = *reinterpret_cast<const half4*>(&h1h[(size_t)u0 * 256 + 4 * t]);
        half4 p1 = *reinterpret_cast<const half4*>(&h1h[(size_t)u1 * 256 + 4 * t]);
        half4 p2 = *reinterpret_cast<const half4*>(&h1h[(size_t)u2 * 256 + 4 * t]);
        half4 p3 = *reinterpret_cast<const half4*>(&h1h[(size_t)u3 * 256 + 4 * t]);
        acc.x += a0 * (float)p0[0] + a1 * (float)p1[0] + a2 * (float)p2[0] + a3 * (float)p3[0];
        acc.y += a0 * (float)p0[1] + a1 * (float)p1[1] + a2 * (float)p2[1] + a3 * (float)p3[1];
        acc.z += a0 * (float)p0[2] + a1 * (float)p1[2] + a2 * (float)p2[2] + a3 * (float)p3[2];
        acc.w += a0 * (float)p0[3] + a1 * (float)p1[3] + a2 * (float)p2[3] + a3 * (float)p3[3];
    }
    for (; i < end; i++) {
        int e = i - start;
        int u0 = src_csr[i];
        float a0;
        if (e < 64) {
            a0 = sc[e][head] * invs;
        } else {
            float x = el[u0 * 8 + head] + erv;
            x = (x >= 0.f) ? x : NEG_SLOPE * x;
            a0 = expf(x) * invs;
        }
        half4 p0 = *reinterpret_cast<const half4*>(&h1h[(size_t)u0 * 256 + 4 * t]);
        acc.x += a0 * (float)p0[0];
        acc.y += a0 * (float)p0[1];
        acc.z += a0 * (float)p0[2];
        acc.w += a0 * (float)p0[3];
    }
    float4 b = *reinterpret_cast<const float4*>(&bias1[4 * t]);
    float ox = acc.x + b.x, oy = acc.y + b.y, oz = acc.z + b.z, ow = acc.w + b.w;
    ox = (ox > 0.f) ? ox : (expf(ox) - 1.f);
    oy = (oy > 0.f) ? oy : (expf(oy) - 1.f);
    oz = (oz > 0.f) ? oz : (expf(oz) - 1.f);
    ow = (ow > 0.f) ? ow : (expf(ow) - 1.f);
    half4 o = {(_Float16)ox, (_Float16)oy, (_Float16)oz, (_Float16)ow};
    *reinterpret_cast<half4*>(&x2[(size_t)v * 256 + 4 * t]) = o;
}

// ---------------- GEMM2: split-bf16 MFMA, BM=64, K-step=128, fp16 h2 out ----------------

__global__ __launch_bounds__(256) void gemm2_mfma(const _Float16* __restrict__ X,
                                                  const float* __restrict__ W2,
                                                  const float* __restrict__ al,
                                                  const float* __restrict__ ar,
                                                  _Float16* __restrict__ h2,
                                                  float* __restrict__ el2,
                                                  float* __restrict__ er2, int M) {
    __shared__ unsigned short Xh[16][64][8], Xl[16][64][8];
    __shared__ unsigned short Wh[32][16][8], Wl[32][16][8];
    int tid = threadIdx.x;
    int lane = tid & 63, wave = tid >> 6;
    int kgl = lane >> 4, rl = lane & 15;
    int row0 = blockIdx.x * 64;

#pragma unroll
    for (int j = 0; j < 16; j++) {
        int e = tid * 16 + j;
        float x = W2[e];
        unsigned short h = f32_to_bf16_rn(x);
        unsigned short l = f32_to_bf16_rn(x - bf16_bits_to_f32(h));
        int k = e >> 4, c = e & 15;
        Wh[k >> 3][c][k & 7] = h;
        Wl[k >> 3][c][k & 7] = l;
    }

    f32x4 acc = (f32x4){0.f, 0.f, 0.f, 0.f};
    int rowX = tid >> 2, kgb = (tid & 3) * 4;
    int grX = row0 + rowX;
    for (int step = 0; step < 2; step++) {
#pragma unroll
        for (int j = 0; j < 4; j++) {
            int kg = kgb + j;
            int kglob = step * 128 + kg * 8;
            unsigned short hs[8], ls[8];
            if (grX < M) {
                half4 a0 = *reinterpret_cast<const half4*>(&X[(size_t)grX * 256 + kglob]);
                half4 a1 = *reinterpret_cast<const half4*>(&X[(size_t)grX * 256 + kglob + 4]);
                float xs[8] = {(float)a0[0], (float)a0[1], (float)a0[2], (float)a0[3],
                               (float)a1[0], (float)a1[1], (float)a1[2], (float)a1[3]};
#pragma unroll
                for (int q = 0; q < 8; q++) {
                    hs[q] = f32_to_bf16_rn(xs[q]);
                    ls[q] = f32_to_bf16_rn(xs[q] - bf16_bits_to_f32(hs[q]));
                }
            } else {
#pragma unroll
                for (int q = 0; q < 8; q++) { hs[q] = 0; ls[q] = 0; }
            }
            *reinterpret_cast<bf16x8*>(&Xh[kg][rowX][0]) = *reinterpret_cast<bf16x8*>(hs);
            *reinterpret_cast<bf16x8*>(&Xl[kg][rowX][0]) = *reinterpret_cast<bf16x8*>(ls);
        }
        __syncthreads();
#pragma unroll
        for (int ks = 0; ks < 4; ks++) {
            int kg = ks * 4 + kgl;
            int kgw = step * 16 + kg;
            bf16x8 a_h = *reinterpret_cast<bf16x8*>(&Xh[kg][wave * 16 + rl][0]);
            bf16x8 a_l = *reinterpret_cast<bf16x8*>(&Xl[kg][wave * 16 + rl][0]);
            bf16x8 b_h = *reinterpret_cast<bf16x8*>(&Wh[kgw][rl][0]);
            bf16x8 b_l = *reinterpret_cast<bf16x8*>(&Wl[kgw][rl][0]);
            acc = __builtin_amdgcn_mfma_f32_16x16x32_bf16(a_h, b_h, acc, 0, 0, 0);
            acc = __builtin_amdgcn_mfma_f32_16x16x32_bf16(a_h, b_l, acc, 0, 0, 0);
            acc = __builtin_amdgcn_mfma_f32_16x16x32_bf16(a_l, b_h, acc, 0, 0, 0);
        }
        __syncthreads();
    }
    float alv = al[rl], arv = ar[rl];
#pragma unroll
    for (int rr = 0; rr < 4; rr++) {
        int grow = row0 + wave * 16 + (lane >> 4) * 4 + rr;
        bool ok = grow < M;
        if (ok) h2[(size_t)grow * 16 + rl] = (_Float16)acc[rr];
        float pl = acc[rr] * alv;
        float pr = acc[rr] * arv;
#pragma unroll
        for (int off = 8; off >= 1; off >>= 1) {
            pl += __shfl_down(pl, off, 16);
            pr += __shfl_down(pr, off, 16);
        }
        if (rl == 0 && ok) {
            el2[grow] = pl;
            er2[grow] = pr;
        }
    }
}

// ---------------- layer-2 fused softmax + aggregation (fp16 h2 gather) ----------------

__global__ __launch_bounds__(64) void agg2_fused(const int* __restrict__ offs,
                                                 const int* __restrict__ deg_arr,
                                                 const int* __restrict__ src_csr,
                                                 const float* __restrict__ el2,
                                                 const float* __restrict__ er2,
                                                 const _Float16* __restrict__ h2,
                                                 const float* __restrict__ bias2,
                                                 float* __restrict__ out) {
    __shared__ float sc2[64];
    int v = blockIdx.x;
    int t = threadIdx.x;
    int start = offs[v];
    int deg = deg_arr[v];
    int end = start + deg;
    int ncache = (deg < 64) ? deg : 64;
    float erv = er2[v];
    float s = 0.f;
    for (int e = t; e < ncache; e += 64) {
        int u = src_csr[start + e];
        float x = el2[u] + erv;
        x = (x >= 0.f) ? x : NEG_SLOPE * x;
        float ex = expf(x);
        sc2[e] = ex;
        s += ex;
    }
    for (int e = 64 + t; e < deg; e += 64) {
        int u = src_csr[start + e];
        float x = el2[u] + erv;
        x = (x >= 0.f) ? x : NEG_SLOPE * x;
        s += expf(x);
    }
#pragma unroll
    for (int off = 32; off >= 1; off >>= 1) s += __shfl_xor(s, off);
    float invs = (s > 0.f) ? 1.f / s : 0.f;
    __syncthreads();
    int eg = t >> 4, d = t & 15;
    float acc = 0.f;
    for (int i = start + eg; i < end; i += 4) {
        int e = i - start;
        int u = src_csr[i];
        float a;
        if (e < 64) {
            a = sc2[e] * invs;
        } else {
            float x = el2[u] + erv;
            x = (x >= 0.f) ? x : NEG_SLOPE * x;
            a = expf(x) * invs;
        }
        acc += a * (float)h2[(size_t)u * 16 + d];
    }
    acc += __shfl_xor(acc, 32);
    acc += __shfl_xor(acc, 16);
    if (t < 16) out[(size_t)v * 16 + t] = acc + bias2[t];
}

// ---------------- launch ----------------

extern "C" void kernel_launch(void* const* d_in, const int* in_sizes, int n_in,
                              void* d_out, int out_size, void* d_ws, size_t ws_size,
                              hipStream_t stream) {
    const float* emb   = (const float*)d_in[0];
    const int*   src   = (const int*)d_in[1];
    const int*   dst   = (const int*)d_in[2];
    const float* W1    = (const float*)d_in[3];
    const float* al1   = (const float*)d_in[4];
    const float* ar1   = (const float*)d_in[5];
    const float* bias1 = (const float*)d_in[6];
    const float* W2    = (const float*)d_in[7];
    const float* al2   = (const float*)d_in[8];
    const float* ar2   = (const float*)d_in[9];
    const float* bias2 = (const float*)d_in[10];
    float* out = (float*)d_out;

    char* ws = (char*)d_ws;
    auto alloc = [&](size_t bytes) -> void* {
        void* p = ws;
        ws += (bytes + 255) & ~(size_t)255;
        return p;
    };
    int* deg     = (int*)alloc((N_NODES + 64) * 4);  // deg + gcounter tail
    int* gcounter = deg + N_NODES;
    int* cursor  = (int*)alloc(N_NODES * 4);
    int* offs    = (int*)alloc(N_NODES * 4);
    int* src_csr = (int*)alloc(N_EDGES * 4);
    unsigned short* W1Th = (unsigned short*)alloc(256 * 256 * 2);
    unsigned short* W1Tl = (unsigned short*)alloc(256 * 256 * 2);
    _Float16* h1h = (_Float16*)alloc((size_t)N_NODES * 256 * 2);
    float* el1   = (float*)alloc(N_NODES * 8 * 4);
    float* er1   = (float*)alloc(N_NODES * 8 * 4);
    _Float16* x2h = (_Float16*)alloc((size_t)N_NODES * 256 * 2);
    _Float16* h2h = (_Float16*)alloc((size_t)N_NODES * 16 * 2);
    float* el2   = (float*)alloc(N_NODES * 4);
    float* er2   = (float*)alloc(N_NODES * 4);

    hipMemsetAsync(deg, 0, (N_NODES + 1) * 4, stream);
    // K1: count_deg (3125) || convert_W1T (256)
    k_count_convert<<<3381, 256, 0, stream>>>(dst, deg, W1, W1Th, W1Tl);
    // K2: full gemm1 (782, ~3 blocks/CU) || assign_offs (196)
    k_gemm1_assign<<<978, 256, 0, stream>>>(emb, W1Th, W1Tl, al1, ar1, h1h, el1, er1,
                                            N_NODES, deg, offs, cursor, gcounter);
    // K3: scatter alone (needs assign complete)
    scatter_edges<<<3125, 256, 0, stream>>>(src, dst, cursor, src_csr);
    agg1_fused<<<N_NODES, 64, 0, stream>>>(offs, deg, src_csr, el1, er1, h1h, bias1, x2h);
    gemm2_mfma<<<(N_NODES + 63) / 64, 256, 0, stream>>>(x2h, W2, al2, ar2, h2h, el2, er2, N_NODES);
    agg2_fused<<<N_NODES, 64, 0, stream>>>(offs, deg, src_csr, el2, er2, h2h, bias2, out);
}

// Round 17
// 221.030 us; speedup vs baseline: 1.0844x; 1.0844x over previous
//
#include <hip/hip_runtime.h>
#include <math.h>

#define N_NODES 50000
#define N_EDGES 800000
#define NEG_SLOPE 0.2f

typedef __attribute__((ext_vector_type(8))) short bf16x8;
typedef __attribute__((ext_vector_type(4))) float f32x4;
typedef __attribute__((ext_vector_type(4))) _Float16 half4;

__device__ inline unsigned short f32_to_bf16_rn(float x) {
    unsigned u = __builtin_bit_cast(unsigned, x);
    unsigned r = u + 0x7fffu + ((u >> 16) & 1u);
    return (unsigned short)(r >> 16);
}
__device__ inline float bf16_bits_to_f32(unsigned short h) {
    unsigned u = ((unsigned)h) << 16;
    return __builtin_bit_cast(float, u);
}
__device__ inline void load_lds16(const void* g, void* l) {
    __builtin_amdgcn_global_load_lds(
        (const __attribute__((address_space(1))) void*)g,
        (__attribute__((address_space(3))) void*)l, 16, 0, 0);
}

// ---------------- bodies ----------------

__device__ __forceinline__ void count_body(int bb, const int* __restrict__ dst,
                                           int* __restrict__ deg) {
    int i = bb * 256 + threadIdx.x;
    if (i < N_EDGES) atomicAdd(&deg[dst[i]], 1);
}

__device__ __forceinline__ void convert_body(int n, const float* __restrict__ W,
                                             unsigned short* __restrict__ Th,
                                             unsigned short* __restrict__ Tl) {
    int k = threadIdx.x;
    float x = W[k * 256 + n];
    unsigned short h = f32_to_bf16_rn(x);
    float lo = x - bf16_bits_to_f32(h);
    size_t idx = ((size_t)(k >> 3) * 256 + n) * 8 + (k & 7);
    Th[idx] = h;
    Tl[idx] = f32_to_bf16_rn(lo);
}

// per-block scan + one global atomic: arbitrary-order disjoint segments
__device__ __forceinline__ void assign_body(int bb, const int* __restrict__ deg,
                                            int* __restrict__ offs,
                                            int* __restrict__ cursor,
                                            int* __restrict__ gcounter) {
    __shared__ int buf[256];
    __shared__ int base;
    int tid = threadIdx.x;
    int v = bb * 256 + tid;
    int d = (v < N_NODES) ? deg[v] : 0;
    buf[tid] = d;
    __syncthreads();
    for (int off = 1; off < 256; off <<= 1) {
        int x = (tid >= off) ? buf[tid - off] : 0;
        __syncthreads();
        buf[tid] += x;
        __syncthreads();
    }
    if (tid == 255) base = atomicAdd(gcounter, buf[255]);
    __syncthreads();
    if (v < N_NODES) {
        int start = base + buf[tid] - d;
        offs[v] = start;
        cursor[v] = start;
    }
}

__device__ __forceinline__ void scatter_body(int bb, const int* __restrict__ src,
                                             const int* __restrict__ dst,
                                             int* __restrict__ cursor,
                                             int* __restrict__ src_csr) {
    int i = bb * 256 + threadIdx.x;
    if (i < N_EDGES) {
        int p = atomicAdd(&cursor[dst[i]], 1);
        src_csr[p] = src[i];
    }
}

// ---------------- GEMM1 body: split-bf16 MFMA, BM=64 BN=256, fused el/er ----------------

__device__ __forceinline__ void gemm1_body(int bb, const float* __restrict__ A,
                                           const unsigned short* __restrict__ BTh,
                                           const unsigned short* __restrict__ BTl,
                                           const float* __restrict__ al,
                                           const float* __restrict__ ar,
                                           _Float16* __restrict__ C,
                                           float* __restrict__ el,
                                           float* __restrict__ er, int M) {
    __shared__ unsigned short Ah[4][64][8], Al[4][64][8];
    __shared__ unsigned short Bh[4][256][8], Bl[4][256][8];
    int tid = threadIdx.x;
    int lane = tid & 63, wave = tid >> 6;
    int kgl = lane >> 4, rl = lane & 15;
    int row0 = bb * 64;

    f32x4 acc[4][4];
#pragma unroll
    for (int i = 0; i < 4; i++)
#pragma unroll
        for (int j = 0; j < 4; j++) acc[i][j] = (f32x4){0.f, 0.f, 0.f, 0.f};

    int rowA = tid >> 2, kgA = tid & 3;
    int grA = row0 + rowA;
    const float* pA = &A[(size_t)grA * 256 + kgA * 8];
    float4 x0 = make_float4(0.f, 0.f, 0.f, 0.f);
    float4 x1 = make_float4(0.f, 0.f, 0.f, 0.f);
    if (grA < M) {
        x0 = *reinterpret_cast<const float4*>(pA);
        x1 = *reinterpret_cast<const float4*>(pA + 4);
    }

    for (int step = 0; step < 8; step++) {
        int k0 = step * 32;
        {
            float xs[8] = {x0.x, x0.y, x0.z, x0.w, x1.x, x1.y, x1.z, x1.w};
            unsigned short hs[8], ls[8];
#pragma unroll
            for (int j = 0; j < 8; j++) {
                hs[j] = f32_to_bf16_rn(xs[j]);
                ls[j] = f32_to_bf16_rn(xs[j] - bf16_bits_to_f32(hs[j]));
            }
            *reinterpret_cast<bf16x8*>(&Ah[kgA][rowA][0]) = *reinterpret_cast<bf16x8*>(hs);
            *reinterpret_cast<bf16x8*>(&Al[kgA][rowA][0]) = *reinterpret_cast<bf16x8*>(ls);
        }
        int s0 = k0 >> 3;
#pragma unroll
        for (int i = 0; i < 4; i++) {
            load_lds16(&BTh[((size_t)(s0 + i) * 256 + tid) * 8], &Bh[i][wave << 6][0]);
            load_lds16(&BTl[((size_t)(s0 + i) * 256 + tid) * 8], &Bl[i][wave << 6][0]);
        }
        __syncthreads();
        if (step < 7 && grA < M) {
            x0 = *reinterpret_cast<const float4*>(pA + (step + 1) * 32);
            x1 = *reinterpret_cast<const float4*>(pA + (step + 1) * 32 + 4);
        }
        bf16x8 a_h[4], a_l[4];
#pragma unroll
        for (int mf = 0; mf < 4; mf++) {
            int row = mf * 16 + rl;
            a_h[mf] = *reinterpret_cast<bf16x8*>(&Ah[kgl][row][0]);
            a_l[mf] = *reinterpret_cast<bf16x8*>(&Al[kgl][row][0]);
        }
#pragma unroll
        for (int nf = 0; nf < 4; nf++) {
            int col = wave * 64 + nf * 16 + rl;
            bf16x8 bh = *reinterpret_cast<bf16x8*>(&Bh[kgl][col][0]);
            bf16x8 bl = *reinterpret_cast<bf16x8*>(&Bl[kgl][col][0]);
#pragma unroll
            for (int mf = 0; mf < 4; mf++) {
                acc[mf][nf] = __builtin_amdgcn_mfma_f32_16x16x32_bf16(a_h[mf], bh, acc[mf][nf], 0, 0, 0);
                acc[mf][nf] = __builtin_amdgcn_mfma_f32_16x16x32_bf16(a_h[mf], bl, acc[mf][nf], 0, 0, 0);
                acc[mf][nf] = __builtin_amdgcn_mfma_f32_16x16x32_bf16(a_l[mf], bh, acc[mf][nf], 0, 0, 0);
            }
        }
        __syncthreads();
    }
    float alv[4], arv[4];
#pragma unroll
    for (int nf = 0; nf < 4; nf++) {
        int c = wave * 64 + nf * 16 + rl;
        alv[nf] = al[c];
        arv[nf] = ar[c];
    }
#pragma unroll
    for (int mf = 0; mf < 4; mf++) {
#pragma unroll
        for (int rr = 0; rr < 4; rr++) {
            int grow = row0 + mf * 16 + (lane >> 4) * 4 + rr;
            bool ok = grow < M;
            if (ok) {
#pragma unroll
                for (int nf = 0; nf < 4; nf++) {
                    int gcol = wave * 64 + nf * 16 + rl;
                    C[(size_t)grow * 256 + gcol] = (_Float16)acc[mf][nf][rr];
                }
            }
            float e0 = acc[mf][0][rr] * alv[0] + acc[mf][1][rr] * alv[1];
            float e1 = acc[mf][2][rr] * alv[2] + acc[mf][3][rr] * alv[3];
            float f0 = acc[mf][0][rr] * arv[0] + acc[mf][1][rr] * arv[1];
            float f1 = acc[mf][2][rr] * arv[2] + acc[mf][3][rr] * arv[3];
#pragma unroll
            for (int off = 8; off >= 1; off >>= 1) {
                e0 += __shfl_down(e0, off, 16);
                e1 += __shfl_down(e1, off, 16);
                f0 += __shfl_down(f0, off, 16);
                f1 += __shfl_down(f1, off, 16);
            }
            if (rl == 0 && ok) {
                int h0 = wave * 2;
                el[grow * 8 + h0] = e0;
                el[grow * 8 + h0 + 1] = e1;
                er[grow * 8 + h0] = f0;
                er[grow * 8 + h0 + 1] = f1;
            }
        }
    }
}

// ---------------- fused launch kernels (R15 schedule) ----------------

__global__ __launch_bounds__(256) void k_count_convert(const int* __restrict__ dst,
                                                       int* __restrict__ deg,
                                                       const float* __restrict__ W1,
                                                       unsigned short* __restrict__ Th,
                                                       unsigned short* __restrict__ Tl) {
    int b = blockIdx.x;
    if (b < 3125) count_body(b, dst, deg);
    else convert_body(b - 3125, W1, Th, Tl);
}

__global__ __launch_bounds__(256) void k_gemmA_assign(const float* __restrict__ A,
                                                      const unsigned short* __restrict__ BTh,
                                                      const unsigned short* __restrict__ BTl,
                                                      const float* __restrict__ al,
                                                      const float* __restrict__ ar,
                                                      _Float16* __restrict__ C,
                                                      float* __restrict__ el,
                                                      float* __restrict__ er, int M,
                                                      const int* __restrict__ deg,
                                                      int* __restrict__ offs,
                                                      int* __restrict__ cursor,
                                                      int* __restrict__ gcounter) {
    int b = blockIdx.x;
    if (b < 391) gemm1_body(b, A, BTh, BTl, al, ar, C, el, er, M);
    else assign_body(b - 391, deg, offs, cursor, gcounter);
}

__global__ __launch_bounds__(256) void k_gemmB_scatter(const float* __restrict__ A,
                                                       const unsigned short* __restrict__ BTh,
                                                       const unsigned short* __restrict__ BTl,
                                                       const float* __restrict__ al,
                                                       const float* __restrict__ ar,
                                                       _Float16* __restrict__ C,
                                                       float* __restrict__ el,
                                                       float* __restrict__ er, int M,
                                                       const int* __restrict__ src,
                                                       const int* __restrict__ dst,
                                                       int* __restrict__ cursor,
                                                       int* __restrict__ src_csr) {
    int b = blockIdx.x;
    if (b < 391) gemm1_body(391 + b, A, BTh, BTl, al, ar, C, el, er, M);
    else scatter_body(b - 391, src, dst, cursor, src_csr);
}

// ---------------- layer-1 fused softmax + weighted gather (1 wave/node) ----------------

__global__ __launch_bounds__(64) void agg1_fused(const int* __restrict__ offs,
                                                 const int* __restrict__ deg_arr,
                                                 const int* __restrict__ src_csr,
                                                 const float* __restrict__ el,
                                                 const float* __restrict__ er,
                                                 const _Float16* __restrict__ h1h,
                                                 const float* __restrict__ bias1,
                                                 _Float16* __restrict__ x2) {
    __shared__ float sc[64][8];
    int v = blockIdx.x;
    int t = threadIdx.x;
    int head = t >> 3, slot = t & 7;
    int start = offs[v];
    int deg = deg_arr[v];
    int end = start + deg;
    int ncache = (deg < 64) ? deg : 64;
    float erv = er[v * 8 + head];
    float s = 0.f;
    for (int base = 0; base < ncache; base += 8) {
        int e = base + slot;
        if (e < ncache) {
            int u = src_csr[start + e];
            float x = el[u * 8 + head] + erv;
            x = (x >= 0.f) ? x : NEG_SLOPE * x;
            float ex = expf(x);
            sc[e][head] = ex;
            s += ex;
        }
    }
    for (int base = 64; base < deg; base += 8) {
        int e = base + slot;
        if (e < deg) {
            int u = src_csr[start + e];
            float x = el[u * 8 + head] + erv;
            x = (x >= 0.f) ? x : NEG_SLOPE * x;
            s += expf(x);
        }
    }
    s += __shfl_xor(s, 1);
    s += __shfl_xor(s, 2);
    s += __shfl_xor(s, 4);
    float invs = (s > 0.f) ? 1.f / s : 0.f;
    __syncthreads();
    float4 acc = make_float4(0.f, 0.f, 0.f, 0.f);
    int i = start;
    for (; i + 3 < end && (i - start) + 3 < 64; i += 4) {
        int e = i - start;
        int u0 = src_csr[i];
        int u1 = src_csr[i + 1];
        int u2 = src_csr[i + 2];
        int u3 = src_csr[i + 3];
        float a0 = sc[e][head] * invs;
        float a1 = sc[e + 1][head] * invs;
        float a2 = sc[e + 2][head] * invs;
        float a3 = sc[e + 3][head] * invs;
        half4 p0 = *reinterpret_cast<const half4*>(&h1h[(size_t)u0 * 256 + 4 * t]);
        half4 p1 = *reinterpret_cast<const half4*>(&h1h[(size_t)u1 * 256 + 4 * t]);
        half4 p2 = *reinterpret_cast<const half4*>(&h1h[(size_t)u2 * 256 + 4 * t]);
        half4 p3 = *reinterpret_cast<const half4*>(&h1h[(size_t)u3 * 256 + 4 * t]);
        acc.x += a0 * (float)p0[0] + a1 * (float)p1[0] + a2 * (float)p2[0] + a3 * (float)p3[0];
        acc.y += a0 * (float)p0[1] + a1 * (float)p1[1] + a2 * (float)p2[1] + a3 * (float)p3[1];
        acc.z += a0 * (float)p0[2] + a1 * (float)p1[2] + a2 * (float)p2[2] + a3 * (float)p3[2];
        acc.w += a0 * (float)p0[3] + a1 * (float)p1[3] + a2 * (float)p2[3] + a3 * (float)p3[3];
    }
    for (; i < end; i++) {
        int e = i - start;
        int u0 = src_csr[i];
        float a0;
        if (e < 64) {
            a0 = sc[e][head] * invs;
        } else {
            float x = el[u0 * 8 + head] + erv;
            x = (x >= 0.f) ? x : NEG_SLOPE * x;
            a0 = expf(x) * invs;
        }
        half4 p0 = *reinterpret_cast<const half4*>(&h1h[(size_t)u0 * 256 + 4 * t]);
        acc.x += a0 * (float)p0[0];
        acc.y += a0 * (float)p0[1];
        acc.z += a0 * (float)p0[2];
        acc.w += a0 * (float)p0[3];
    }
    float4 b = *reinterpret_cast<const float4*>(&bias1[4 * t]);
    float ox = acc.x + b.x, oy = acc.y + b.y, oz = acc.z + b.z, ow = acc.w + b.w;
    ox = (ox > 0.f) ? ox : (expf(ox) - 1.f);
    oy = (oy > 0.f) ? oy : (expf(oy) - 1.f);
    oz = (oz > 0.f) ? oz : (expf(oz) - 1.f);
    ow = (ow > 0.f) ? ow : (expf(ow) - 1.f);
    half4 o = {(_Float16)ox, (_Float16)oy, (_Float16)oz, (_Float16)ow};
    *reinterpret_cast<half4*>(&x2[(size_t)v * 256 + 4 * t]) = o;
}

// ---------------- GEMM2: split-bf16 MFMA, BM=64, K-step=128, fp16 h2 out ----------------

__global__ __launch_bounds__(256) void gemm2_mfma(const _Float16* __restrict__ X,
                                                  const float* __restrict__ W2,
                                                  const float* __restrict__ al,
                                                  const float* __restrict__ ar,
                                                  _Float16* __restrict__ h2,
                                                  float* __restrict__ el2,
                                                  float* __restrict__ er2, int M) {
    __shared__ unsigned short Xh[16][64][8], Xl[16][64][8];
    __shared__ unsigned short Wh[32][16][8], Wl[32][16][8];
    int tid = threadIdx.x;
    int lane = tid & 63, wave = tid >> 6;
    int kgl = lane >> 4, rl = lane & 15;
    int row0 = blockIdx.x * 64;

#pragma unroll
    for (int j = 0; j < 16; j++) {
        int e = tid * 16 + j;
        float x = W2[e];
        unsigned short h = f32_to_bf16_rn(x);
        unsigned short l = f32_to_bf16_rn(x - bf16_bits_to_f32(h));
        int k = e >> 4, c = e & 15;
        Wh[k >> 3][c][k & 7] = h;
        Wl[k >> 3][c][k & 7] = l;
    }

    f32x4 acc = (f32x4){0.f, 0.f, 0.f, 0.f};
    int rowX = tid >> 2, kgb = (tid & 3) * 4;
    int grX = row0 + rowX;
    for (int step = 0; step < 2; step++) {
#pragma unroll
        for (int j = 0; j < 4; j++) {
            int kg = kgb + j;
            int kglob = step * 128 + kg * 8;
            unsigned short hs[8], ls[8];
            if (grX < M) {
                half4 a0 = *reinterpret_cast<const half4*>(&X[(size_t)grX * 256 + kglob]);
                half4 a1 = *reinterpret_cast<const half4*>(&X[(size_t)grX * 256 + kglob + 4]);
                float xs[8] = {(float)a0[0], (float)a0[1], (float)a0[2], (float)a0[3],
                               (float)a1[0], (float)a1[1], (float)a1[2], (float)a1[3]};
#pragma unroll
                for (int q = 0; q < 8; q++) {
                    hs[q] = f32_to_bf16_rn(xs[q]);
                    ls[q] = f32_to_bf16_rn(xs[q] - bf16_bits_to_f32(hs[q]));
                }
            } else {
#pragma unroll
                for (int q = 0; q < 8; q++) { hs[q] = 0; ls[q] = 0; }
            }
            *reinterpret_cast<bf16x8*>(&Xh[kg][rowX][0]) = *reinterpret_cast<bf16x8*>(hs);
            *reinterpret_cast<bf16x8*>(&Xl[kg][rowX][0]) = *reinterpret_cast<bf16x8*>(ls);
        }
        __syncthreads();
#pragma unroll
        for (int ks = 0; ks < 4; ks++) {
            int kg = ks * 4 + kgl;
            int kgw = step * 16 + kg;
            bf16x8 a_h = *reinterpret_cast<bf16x8*>(&Xh[kg][wave * 16 + rl][0]);
            bf16x8 a_l = *reinterpret_cast<bf16x8*>(&Xl[kg][wave * 16 + rl][0]);
            bf16x8 b_h = *reinterpret_cast<bf16x8*>(&Wh[kgw][rl][0]);
            bf16x8 b_l = *reinterpret_cast<bf16x8*>(&Wl[kgw][rl][0]);
            acc = __builtin_amdgcn_mfma_f32_16x16x32_bf16(a_h, b_h, acc, 0, 0, 0);
            acc = __builtin_amdgcn_mfma_f32_16x16x32_bf16(a_h, b_l, acc, 0, 0, 0);
            acc = __builtin_amdgcn_mfma_f32_16x16x32_bf16(a_l, b_h, acc, 0, 0, 0);
        }
        __syncthreads();
    }
    float alv = al[rl], arv = ar[rl];
#pragma unroll
    for (int rr = 0; rr < 4; rr++) {
        int grow = row0 + wave * 16 + (lane >> 4) * 4 + rr;
        bool ok = grow < M;
        if (ok) h2[(size_t)grow * 16 + rl] = (_Float16)acc[rr];
        float pl = acc[rr] * alv;
        float pr = acc[rr] * arv;
#pragma unroll
        for (int off = 8; off >= 1; off >>= 1) {
            pl += __shfl_down(pl, off, 16);
            pr += __shfl_down(pr, off, 16);
        }
        if (rl == 0 && ok) {
            el2[grow] = pl;
            er2[grow] = pr;
        }
    }
}

// ---------------- layer-2 fused softmax + aggregation (fp16 h2 gather) ----------------

__global__ __launch_bounds__(64) void agg2_fused(const int* __restrict__ offs,
                                                 const int* __restrict__ deg_arr,
                                                 const int* __restrict__ src_csr,
                                                 const float* __restrict__ el2,
                                                 const float* __restrict__ er2,
                                                 const _Float16* __restrict__ h2,
                                                 const float* __restrict__ bias2,
                                                 float* __restrict__ out) {
    __shared__ float sc2[64];
    int v = blockIdx.x;
    int t = threadIdx.x;
    int start = offs[v];
    int deg = deg_arr[v];
    int end = start + deg;
    int ncache = (deg < 64) ? deg : 64;
    float erv = er2[v];
    float s = 0.f;
    for (int e = t; e < ncache; e += 64) {
        int u = src_csr[start + e];
        float x = el2[u] + erv;
        x = (x >= 0.f) ? x : NEG_SLOPE * x;
        float ex = expf(x);
        sc2[e] = ex;
        s += ex;
    }
    for (int e = 64 + t; e < deg; e += 64) {
        int u = src_csr[start + e];
        float x = el2[u] + erv;
        x = (x >= 0.f) ? x : NEG_SLOPE * x;
        s += expf(x);
    }
#pragma unroll
    for (int off = 32; off >= 1; off >>= 1) s += __shfl_xor(s, off);
    float invs = (s > 0.f) ? 1.f / s : 0.f;
    __syncthreads();
    int eg = t >> 4, d = t & 15;
    float acc = 0.f;
    for (int i = start + eg; i < end; i += 4) {
        int e = i - start;
        int u = src_csr[i];
        float a;
        if (e < 64) {
            a = sc2[e] * invs;
        } else {
            float x = el2[u] + erv;
            x = (x >= 0.f) ? x : NEG_SLOPE * x;
            a = expf(x) * invs;
        }
        acc += a * (float)h2[(size_t)u * 16 + d];
    }
    acc += __shfl_xor(acc, 32);
    acc += __shfl_xor(acc, 16);
    if (t < 16) out[(size_t)v * 16 + t] = acc + bias2[t];
}

// ---------------- launch ----------------

extern "C" void kernel_launch(void* const* d_in, const int* in_sizes, int n_in,
                              void* d_out, int out_size, void* d_ws, size_t ws_size,
                              hipStream_t stream) {
    const float* emb   = (const float*)d_in[0];
    const int*   src   = (const int*)d_in[1];
    const int*   dst   = (const int*)d_in[2];
    const float* W1    = (const float*)d_in[3];
    const float* al1   = (const float*)d_in[4];
    const float* ar1   = (const float*)d_in[5];
    const float* bias1 = (const float*)d_in[6];
    const float* W2    = (const float*)d_in[7];
    const float* al2   = (const float*)d_in[8];
    const float* ar2   = (const float*)d_in[9];
    const float* bias2 = (const float*)d_in[10];
    float* out = (float*)d_out;

    char* ws = (char*)d_ws;
    auto alloc = [&](size_t bytes) -> void* {
        void* p = ws;
        ws += (bytes + 255) & ~(size_t)255;
        return p;
    };
    int* deg     = (int*)alloc((N_NODES + 64) * 4);  // deg + gcounter tail
    int* gcounter = deg + N_NODES;
    int* cursor  = (int*)alloc(N_NODES * 4);
    int* offs    = (int*)alloc(N_NODES * 4);
    int* src_csr = (int*)alloc(N_EDGES * 4);
    unsigned short* W1Th = (unsigned short*)alloc(256 * 256 * 2);
    unsigned short* W1Tl = (unsigned short*)alloc(256 * 256 * 2);
    _Float16* h1h = (_Float16*)alloc((size_t)N_NODES * 256 * 2);
    float* el1   = (float*)alloc(N_NODES * 8 * 4);
    float* er1   = (float*)alloc(N_NODES * 8 * 4);
    _Float16* x2h = (_Float16*)alloc((size_t)N_NODES * 256 * 2);
    _Float16* h2h = (_Float16*)alloc((size_t)N_NODES * 16 * 2);
    float* el2   = (float*)alloc(N_NODES * 4);
    float* er2   = (float*)alloc(N_NODES * 4);

    hipMemsetAsync(deg, 0, (N_NODES + 1) * 4, stream);
    // K1: count_deg (3125) || convert_W1T (256)
    k_count_convert<<<3381, 256, 0, stream>>>(dst, deg, W1, W1Th, W1Tl);
    // K2: gemm1 blocks 0..390 || assign_offs (196)
    k_gemmA_assign<<<587, 256, 0, stream>>>(emb, W1Th, W1Tl, al1, ar1, h1h, el1, er1,
                                            N_NODES, deg, offs, cursor, gcounter);
    // K3: gemm1 blocks 391..781 || scatter_edges (3125)
    k_gemmB_scatter<<<3516, 256, 0, stream>>>(emb, W1Th, W1Tl, al1, ar1, h1h, el1, er1,
                                              N_NODES, src, dst, cursor, src_csr);
    agg1_fused<<<N_NODES, 64, 0, stream>>>(offs, deg, src_csr, el1, er1, h1h, bias1, x2h);
    gemm2_mfma<<<(N_NODES + 63) / 64, 256, 0, stream>>>(x2h, W2, al2, ar2, h2h, el2, er2, N_NODES);
    agg2_fused<<<N_NODES, 64, 0, stream>>>(offs, deg, src_csr, el2, er2, h2h, bias2, out);
}